// Round 2
// baseline (1204.798 us; speedup 1.0000x reference)
//
#include <hip/hip_runtime.h>

#define VOCAB 32000
#define EMB 64
#define NROWS 8192                 // B*S = 2*4096
#define VSPLITS 50
#define VCHUNK (VOCAB / VSPLITS)   // 640
#define VT 64                      // vocab rows per LDS tile
#define TILES (VCHUNK / VT)        // 10
#define ROWS_PER_BLOCK 512         // 256 threads x 2 rows/thread

typedef float f4nt __attribute__((ext_vector_type(4)));

// Monotone order-preserving f32 -> u32 map (equal floats -> equal keys).
__device__ __forceinline__ unsigned enc_f32(float f) {
    unsigned u = __float_as_uint(f);
    return (u & 0x80000000u) ? ~u : (u | 0x80000000u);
}

// ---------------- k1: inverse norms + zero the packed argmax keys ----------------
__global__ void wnorm_init_kernel(const float* __restrict__ W, float* __restrict__ invn,
                                  unsigned long long* __restrict__ packed) {
    int v = blockIdx.x * blockDim.x + threadIdx.x;
    if (v < NROWS) packed[v] = 0ull;   // below every encoded real value
    if (v >= VOCAB) return;
    const float4* w4 = (const float4*)(W + (size_t)v * EMB);
    float s = 0.f;
    #pragma unroll
    for (int q = 0; q < 16; ++q) {
        float4 w = w4[q];
        s += w.x * w.x + w.y * w.y + w.z * w.z + w.w * w.w;
    }
    invn[v] = 1.0f / sqrtf(s);
}

// ---------------- k2: argmax over a V-chunk, 2 rows per thread ----------------
// grid: (NROWS/512, VSPLITS). Each thread owns 2 rows (128 VGPRs of A);
// W streamed through LDS in 64-row tiles; all threads read the same wt[]
// address simultaneously -> broadcast (conflict-free). 16 ds_read_b128 now
// feed 128 FMAs -> VALU-bound instead of LDS-pipe-bound.
__global__ __launch_bounds__(256, 3) void argmax_partial_kernel(
    const float* __restrict__ x, const float* __restrict__ W,
    const float* __restrict__ invn, unsigned long long* __restrict__ packed)
{
    __shared__ float4 wt[VT * 16];   // 64 v x 64 d = 16 KB
    __shared__ float  invt[VT];

    const int tid = threadIdx.x;
    const int r0 = blockIdx.x * ROWS_PER_BLOCK + tid;
    const int r1 = r0 + 256;
    const int v0base = blockIdx.y * VCHUNK;

    float4 a0[16], a1[16];
    const float4* A0 = (const float4*)(x + (size_t)r0 * EMB);
    const float4* A1 = (const float4*)(x + (size_t)r1 * EMB);
    #pragma unroll
    for (int q = 0; q < 16; ++q) { a0[q] = A0[q]; a1[q] = A1[q]; }

    float best0 = -1e30f, best1 = -1e30f;
    int bi0 = 0, bi1 = 0;

    for (int t = 0; t < TILES; ++t) {
        const int v0 = v0base + t * VT;
        const float4* wg = (const float4*)(W + (size_t)v0 * EMB);
        #pragma unroll
        for (int q = 0; q < 4; ++q)
            wt[tid + q * 256] = wg[tid + q * 256];
        if (tid < VT) invt[tid] = invn[v0 + tid];
        __syncthreads();

        for (int vv = 0; vv < VT; ++vv) {
            float p0 = 0.f, p1 = 0.f, p2 = 0.f, p3 = 0.f;
            float q0 = 0.f, q1 = 0.f, q2 = 0.f, q3 = 0.f;
            #pragma unroll
            for (int q = 0; q < 16; ++q) {
                float4 w = wt[vv * 16 + q];
                p0 = fmaf(a0[q].x, w.x, p0);
                p1 = fmaf(a0[q].y, w.y, p1);
                p2 = fmaf(a0[q].z, w.z, p2);
                p3 = fmaf(a0[q].w, w.w, p3);
                q0 = fmaf(a1[q].x, w.x, q0);
                q1 = fmaf(a1[q].y, w.y, q1);
                q2 = fmaf(a1[q].z, w.z, q2);
                q3 = fmaf(a1[q].w, w.w, q3);
            }
            // identical accumulation/rounding order to the passing round-1 kernel
            float s0 = ((p0 + p1) + (p2 + p3)) * invt[vv];
            float s1 = ((q0 + q1) + (q2 + q3)) * invt[vv];
            // ascending v + strict '>' => first max index (numpy argmax)
            if (s0 > best0) { best0 = s0; bi0 = v0 + vv; }
            if (s1 > best1) { best1 = s1; bi1 = v0 + vv; }
        }
        __syncthreads();
    }
    // key: larger value wins; equal value -> larger ~idx wins = smaller idx
    unsigned long long k0 = ((unsigned long long)enc_f32(best0) << 32) | (unsigned)(~bi0);
    unsigned long long k1 = ((unsigned long long)enc_f32(best1) << 32) | (unsigned)(~bi1);
    atomicMax(&packed[r0], k0);
    atomicMax(&packed[r1], k1);
}

// ---------------- k3: fused zero + one-hot write (1.048 GB) ----------------
__global__ void onehot_kernel(const unsigned long long* __restrict__ packed,
                              float4* __restrict__ out) {
    const unsigned V4 = VOCAB / 4;                 // 8000 float4 per row
    const unsigned total = (unsigned)NROWS * V4;   // 65,536,000
    unsigned i = blockIdx.x * blockDim.x + threadIdx.x;
    const unsigned stride = gridDim.x * blockDim.x;
    for (; i < total; i += stride) {
        unsigned row = i / V4;           // magic-mul division
        unsigned j = i - row * V4;
        int id = (int)(~(unsigned)packed[row]);    // decode argmax index
        int base = (int)(j * 4);
        f4nt r;
        r.x = (id == base    ) ? 1.f : 0.f;
        r.y = (id == base + 1) ? 1.f : 0.f;
        r.z = (id == base + 2) ? 1.f : 0.f;
        r.w = (id == base + 3) ? 1.f : 0.f;
        __builtin_nontemporal_store(r, (f4nt*)&out[i]);
    }
}

extern "C" void kernel_launch(void* const* d_in, const int* in_sizes, int n_in,
                              void* d_out, int out_size, void* d_ws, size_t ws_size,
                              hipStream_t stream) {
    const float* x = (const float*)d_in[0];   // [2,4096,64]
    const float* W = (const float*)d_in[1];   // [32000,64]
    float* out = (float*)d_out;

    char* ws = (char*)d_ws;
    float* invn = (float*)(ws);                                  // 32000 f = 128000 B
    unsigned long long* packed = (unsigned long long*)(ws + 128000); // 8192 u64 = 65536 B

    wnorm_init_kernel<<<dim3((VOCAB + 255) / 256), dim3(256), 0, stream>>>(W, invn, packed);

    argmax_partial_kernel<<<dim3(NROWS / ROWS_PER_BLOCK, VSPLITS), dim3(256), 0, stream>>>(
        x, W, invn, packed);

    onehot_kernel<<<dim3(2048), dim3(256), 0, stream>>>(packed, (float4*)out);
}

// Round 3
// 425.174 us; speedup vs baseline: 2.8337x; 2.8337x over previous
//
#include <hip/hip_runtime.h>

#define VOCAB 32000
#define EMB 64
#define NROWS 8192                // B*S
#define NCHUNKS 50
#define CCOLS (VOCAB / NCHUNKS)   // 640
#define CTILES (CCOLS / 16)       // 40
#define CAND_MAX 131072

typedef __attribute__((ext_vector_type(8))) short bf16x8;
typedef __attribute__((ext_vector_type(4))) float f32x4;
typedef float f4nt __attribute__((ext_vector_type(4)));

// Monotone order-preserving f32 -> u32 (equal floats -> equal keys).
__device__ __forceinline__ unsigned enc_f32(float f) {
    unsigned u = __float_as_uint(f);
    return (u & 0x80000000u) ? ~u : (u | 0x80000000u);
}
__device__ __forceinline__ float dec_f32(unsigned e) {
    unsigned u = (e & 0x80000000u) ? (e & 0x7fffffffu) : ~e;
    return __uint_as_float(u);
}
// f32 -> bf16 round-to-nearest-even (inputs are Gaussian: no NaN/Inf).
__device__ __forceinline__ unsigned short f2bf(float f) {
    unsigned u = __float_as_uint(f);
    return (unsigned short)((u + 0x7fffu + ((u >> 16) & 1u)) >> 16);
}

// ---- setup: Wbar16 = bf16(W*invn), A16 = bf16(x), norms, init scratch ----
__global__ __launch_bounds__(256) void setup_kernel(
    const float* __restrict__ x, const float* __restrict__ W,
    unsigned short* __restrict__ A16, unsigned short* __restrict__ WB16,
    float* __restrict__ invn, float* __restrict__ normA,
    unsigned* __restrict__ rowmax, unsigned* __restrict__ counter)
{
    int i = blockIdx.x * blockDim.x + threadIdx.x;
    if (i == 0) *counter = 0u;
    if (i < NROWS) rowmax[i] = 0u;
    if (i < VOCAB) {
        const float4* w4 = (const float4*)(W + (size_t)i * EMB);
        float4 buf[16];
        float s = 0.f;
        #pragma unroll
        for (int q = 0; q < 16; ++q) {
            float4 w = w4[q]; buf[q] = w;
            s += w.x * w.x + w.y * w.y + w.z * w.z + w.w * w.w;
        }
        float inv = 1.0f / sqrtf(s);
        invn[i] = inv;
        ushort4* dst = (ushort4*)(WB16 + (size_t)i * EMB);
        #pragma unroll
        for (int q = 0; q < 16; ++q) {
            float4 w = buf[q];
            ushort4 u;
            u.x = f2bf(w.x * inv); u.y = f2bf(w.y * inv);
            u.z = f2bf(w.z * inv); u.w = f2bf(w.w * inv);
            dst[q] = u;
        }
    }
    if (i < NROWS) {
        const float4* a4 = (const float4*)(x + (size_t)i * EMB);
        float4 buf[16];
        float s = 0.f;
        #pragma unroll
        for (int q = 0; q < 16; ++q) {
            float4 a = a4[q]; buf[q] = a;
            s += a.x * a.x + a.y * a.y + a.z * a.z + a.w * a.w;
        }
        normA[i] = sqrtf(s);
        ushort4* dst = (ushort4*)(A16 + (size_t)i * EMB);
        #pragma unroll
        for (int q = 0; q < 16; ++q) {
            float4 a = buf[q];
            ushort4 u;
            u.x = f2bf(a.x); u.y = f2bf(a.y); u.z = f2bf(a.z); u.w = f2bf(a.w);
            dst[q] = u;
        }
    }
}

// ---- pass 1: per-row max of approx sims (bf16 MFMA) ----
// Wave = 64 rows (4 sub-tiles of 16) x 640-col chunk. Fragment maps
// (gfx950 16x16x32 bf16, m89/m92-verified): A/B lane l holds 8 contiguous
// k at (idx = l&15, k0 = (l>>4)*8); C/D: col = l&15, row = (l>>4)*4 + reg.
__global__ __launch_bounds__(256) void pass1_kernel(
    const unsigned short* __restrict__ A16,
    const unsigned short* __restrict__ WB16,
    unsigned* __restrict__ rowmax)
{
    const int lane = threadIdx.x & 63, wid = threadIdx.x >> 6;
    const int lr = lane & 15, lg = lane >> 4;
    const int m0 = blockIdx.x * 256 + wid * 64;
    const int n0 = blockIdx.y * CCOLS;

    bf16x8 a[4][2];
    #pragma unroll
    for (int r = 0; r < 4; ++r)
        #pragma unroll
        for (int kk = 0; kk < 2; ++kk)
            a[r][kk] = *(const bf16x8*)(A16 + (size_t)(m0 + r * 16 + lr) * EMB + kk * 32 + lg * 8);

    float best[4][4];
    #pragma unroll
    for (int r = 0; r < 4; ++r)
        #pragma unroll
        for (int j = 0; j < 4; ++j) best[r][j] = -3e38f;

    const unsigned short* wb = WB16 + (size_t)(n0 + lr) * EMB + lg * 8;
    for (int t = 0; t < CTILES; ++t) {
        bf16x8 b0 = *(const bf16x8*)(wb);
        bf16x8 b1 = *(const bf16x8*)(wb + 32);
        wb += 16 * EMB;
        #pragma unroll
        for (int r = 0; r < 4; ++r) {
            f32x4 acc = {0.f, 0.f, 0.f, 0.f};
            acc = __builtin_amdgcn_mfma_f32_16x16x32_bf16(a[r][0], b0, acc, 0, 0, 0);
            acc = __builtin_amdgcn_mfma_f32_16x16x32_bf16(a[r][1], b1, acc, 0, 0, 0);
            #pragma unroll
            for (int j = 0; j < 4; ++j) best[r][j] = fmaxf(best[r][j], acc[j]);
        }
    }
    #pragma unroll
    for (int r = 0; r < 4; ++r)
        #pragma unroll
        for (int j = 0; j < 4; ++j) {
            float v = best[r][j];
            v = fmaxf(v, __shfl_xor(v, 1));
            v = fmaxf(v, __shfl_xor(v, 2));
            v = fmaxf(v, __shfl_xor(v, 4));
            v = fmaxf(v, __shfl_xor(v, 8));
            if (lr == 0) atomicMax(&rowmax[m0 + r * 16 + lg * 4 + j], enc_f32(v));
        }
}

// ---- thresholds: thr = approx_max - 2*(2^-8)*|A|*1.15 ; init final keys ----
__global__ void thr_kernel(const unsigned* __restrict__ rowmax,
                           const float* __restrict__ normA,
                           float* __restrict__ rowthr,
                           unsigned long long* __restrict__ fin) {
    int i = blockIdx.x * blockDim.x + threadIdx.x;
    if (i < NROWS) {
        rowthr[i] = dec_f32(rowmax[i]) - 0.009f * normA[i];
        fin[i] = 0ull;
    }
}

// ---- pass 2: recompute (bitwise-identical) + collect candidates ----
__global__ __launch_bounds__(256) void pass2_kernel(
    const unsigned short* __restrict__ A16,
    const unsigned short* __restrict__ WB16,
    const float* __restrict__ rowthr,
    unsigned* __restrict__ counter, uint2* __restrict__ cand)
{
    const int lane = threadIdx.x & 63, wid = threadIdx.x >> 6;
    const int lr = lane & 15, lg = lane >> 4;
    const int m0 = blockIdx.x * 256 + wid * 64;
    const int n0 = blockIdx.y * CCOLS;

    bf16x8 a[4][2];
    #pragma unroll
    for (int r = 0; r < 4; ++r)
        #pragma unroll
        for (int kk = 0; kk < 2; ++kk)
            a[r][kk] = *(const bf16x8*)(A16 + (size_t)(m0 + r * 16 + lr) * EMB + kk * 32 + lg * 8);

    float thr[4][4];
    #pragma unroll
    for (int r = 0; r < 4; ++r)
        #pragma unroll
        for (int j = 0; j < 4; ++j) thr[r][j] = rowthr[m0 + r * 16 + lg * 4 + j];

    const unsigned short* wb = WB16 + (size_t)(n0 + lr) * EMB + lg * 8;
    for (int t = 0; t < CTILES; ++t) {
        bf16x8 b0 = *(const bf16x8*)(wb);
        bf16x8 b1 = *(const bf16x8*)(wb + 32);
        wb += 16 * EMB;
        f32x4 accs[4];
        float mx = -1.f;
        #pragma unroll
        for (int r = 0; r < 4; ++r) {
            f32x4 acc = {0.f, 0.f, 0.f, 0.f};
            acc = __builtin_amdgcn_mfma_f32_16x16x32_bf16(a[r][0], b0, acc, 0, 0, 0);
            acc = __builtin_amdgcn_mfma_f32_16x16x32_bf16(a[r][1], b1, acc, 0, 0, 0);
            accs[r] = acc;
            #pragma unroll
            for (int j = 0; j < 4; ++j) mx = fmaxf(mx, acc[j] - thr[r][j]);
        }
        if (mx >= 0.f) {   // rare (~1 in 6000 lanes)
            #pragma unroll
            for (int r = 0; r < 4; ++r)
                #pragma unroll
                for (int j = 0; j < 4; ++j)
                    if (accs[r][j] >= thr[r][j]) {
                        unsigned pos = atomicAdd(counter, 1u);
                        if (pos < CAND_MAX)
                            cand[pos] = make_uint2((unsigned)(m0 + r * 16 + lg * 4 + j),
                                                   (unsigned)(n0 + t * 16 + lr));
                    }
        }
    }
}

// ---- pass 3: exact fp32 re-score of candidates, packed argmax ----
__global__ __launch_bounds__(256) void pass3_kernel(
    const float* __restrict__ x, const float* __restrict__ W,
    const float* __restrict__ invn, const unsigned* __restrict__ counter,
    const uint2* __restrict__ cand, unsigned long long* __restrict__ fin)
{
    unsigned cnt = *counter;
    if (cnt > CAND_MAX) cnt = CAND_MAX;
    for (unsigned i = blockIdx.x * blockDim.x + threadIdx.x; i < cnt;
         i += gridDim.x * blockDim.x) {
        unsigned row = cand[i].x, v = cand[i].y;
        const float4* a4 = (const float4*)(x + (size_t)row * EMB);
        const float4* w4 = (const float4*)(W + (size_t)v * EMB);
        float p0 = 0.f, p1 = 0.f, p2 = 0.f, p3 = 0.f;
        #pragma unroll
        for (int q = 0; q < 16; ++q) {
            float4 aa = a4[q]; float4 ww = w4[q];
            p0 = fmaf(aa.x, ww.x, p0);
            p1 = fmaf(aa.y, ww.y, p1);
            p2 = fmaf(aa.z, ww.z, p2);
            p3 = fmaf(aa.w, ww.w, p3);
        }
        float s = ((p0 + p1) + (p2 + p3)) * invn[v];
        // larger sim wins; equal sim -> larger ~v = smaller v (numpy tie-break)
        unsigned long long k = ((unsigned long long)enc_f32(s) << 32) | (unsigned)(~v);
        atomicMax(&fin[row], k);
    }
}

// ---- one-hot: fused zero + scatter, 1.048 GB nontemporal stream ----
__global__ void onehot_kernel(const unsigned long long* __restrict__ fin,
                              float4* __restrict__ out) {
    const unsigned V4 = VOCAB / 4;
    const unsigned total = (unsigned)NROWS * V4;
    unsigned i = blockIdx.x * blockDim.x + threadIdx.x;
    const unsigned stride = gridDim.x * blockDim.x;
    for (; i < total; i += stride) {
        unsigned row = i / V4;
        unsigned j = i - row * V4;
        int id = (int)(~(unsigned)fin[row]);   // low 32 bits = ~argmax
        int base = (int)(j * 4);
        f4nt r;
        r.x = (id == base    ) ? 1.f : 0.f;
        r.y = (id == base + 1) ? 1.f : 0.f;
        r.z = (id == base + 2) ? 1.f : 0.f;
        r.w = (id == base + 3) ? 1.f : 0.f;
        __builtin_nontemporal_store(r, (f4nt*)&out[i]);
    }
}

extern "C" void kernel_launch(void* const* d_in, const int* in_sizes, int n_in,
                              void* d_out, int out_size, void* d_ws, size_t ws_size,
                              hipStream_t stream) {
    const float* x = (const float*)d_in[0];   // [2,4096,64]
    const float* W = (const float*)d_in[1];   // [32000,64]
    float* out = (float*)d_out;

    char* ws = (char*)d_ws;
    unsigned short* WB16  = (unsigned short*)(ws);                    // 4,096,000
    unsigned short* A16   = (unsigned short*)(ws + 4096000);          // 1,048,576
    float* invn           = (float*)(ws + 5144576);                   //   128,000
    float* normA          = (float*)(ws + 5272576);                   //    32,768
    unsigned* rowmax      = (unsigned*)(ws + 5305344);                //    32,768
    float* rowthr         = (float*)(ws + 5338112);                   //    32,768
    unsigned long long* fin = (unsigned long long*)(ws + 5370880);    //    65,536
    unsigned* counter     = (unsigned*)(ws + 5436416);                //        16
    uint2* cand           = (uint2*)(ws + 5436432);                   // 1,048,576

    setup_kernel<<<dim3((VOCAB + 255) / 256), dim3(256), 0, stream>>>(
        x, W, A16, WB16, invn, normA, rowmax, counter);

    pass1_kernel<<<dim3(NROWS / 256, NCHUNKS), dim3(256), 0, stream>>>(A16, WB16, rowmax);

    thr_kernel<<<dim3(NROWS / 256), dim3(256), 0, stream>>>(rowmax, normA, rowthr, fin);

    pass2_kernel<<<dim3(NROWS / 256, NCHUNKS), dim3(256), 0, stream>>>(
        A16, WB16, rowthr, counter, cand);

    pass3_kernel<<<dim3(64), dim3(256), 0, stream>>>(x, W, invn, counter, cand, fin);

    onehot_kernel<<<dim3(2048), dim3(256), 0, stream>>>(fin, (float4*)out);
}